// Round 11
// baseline (84.767 us; speedup 1.0000x reference)
//
#include <hip/hip_runtime.h>
#include <math.h>

// DetectionLayer: x(32,255,76,76) f32 -> out(32,17328,85) f32
// Block (256 thr) = (b, row i, j-quarter jq). JW = 20/20/20/16 cols.
// Phase A: batched float4 loads (NQ=5|4 vec4 per channel, 16B-aligned).
// Phase B: transform in registers; corner channels (t<4, 12/255) load the
//          cache-warm partner channel (c+-2) and finalize inline; a = c/85
//          exact. LDS write in output layout lds[j*255+c] (~2-way banks,
//          free on CDNA4).
// Phase C: one __syncthreads (loads already consumed -> cheap drain), then
//          contiguous float4 dump (5100|4080 floats, 16B-aligned).
// LDS 20400B -> 8 blocks/CU x 4 waves = 32 waves/CU in 8 INDEPENDENT barrier
// domains (vs R8's 4): block churn + barrier stalls overlap across blocks.
// XCD swizzle: logical (b,i,jq), jq fastest (quarters of a row share an XCD
// -> boundary-line L2 reuse); 9728%8==0 -> bijective.

#define NCH    255
#define NATTR  85
#define HW     5776
#define GW     76
#define NBATCH 32
#define BLOCK  256
#define NWG    (NBATCH * GW * 4)   // 9728
#define CHUNK  (NWG / 8)           // 1216

__device__ __forceinline__ float sigm(float x) {
    return __builtin_amdgcn_rcpf(1.0f + __expf(-x));
}

template<int NQ>   // float4 units per channel: 5 (jq 0..2) or 4 (jq 3)
__device__ __forceinline__ void run_quarter(const float* __restrict__ src,
                                            float* __restrict__ dst,
                                            float* __restrict__ lds,
                                            int jg0, float fi) {
    constexpr int NU  = NCH * NQ;                  // 1275 / 1020
    constexpr int NIT = (NU + BLOCK - 1) / BLOCK;  // 5 / 4

    float4 xv[NIT];

    // ---- phase A: batched float4 loads ----
    #pragma unroll
    for (int k = 0; k < NIT; ++k) {
        int e = threadIdx.x + BLOCK * k;
        if (e < NU) {
            int c = e / NQ, q = e - c * NQ;
            xv[k] = *(const float4*)(src + (size_t)c * HW + 4 * q);
        }
    }

    // ---- phase B: transform + output-layout LDS write ----
    #pragma unroll
    for (int k = 0; k < NIT; ++k) {
        int e = threadIdx.x + BLOCK * k;
        if (e < NU) {
            int c = e / NQ, q = e - c * NQ;
            int a = c / 85;              // exact
            int t = c - 85 * a;
            float4 v = xv[k];
            float r0, r1, r2, r3;
            if (t >= 4) {
                r0 = sigm(v.x); r1 = sigm(v.y); r2 = sigm(v.z); r3 = sigm(v.w);
            } else {
                int cp = (t < 2) ? c + 2 : c - 2;      // partner (cache-warm)
                float4 pv = *(const float4*)(src + (size_t)cp * HW + 4 * q);
                float ancw = (a == 0) ? 10.f : (a == 1) ? 16.f : 33.f;
                float anch = (a == 0) ? 13.f : (a == 1) ? 30.f : 23.f;
                float anc  = ((t & 1) ? anch : ancw) * (0.5f / 608.f);
                float vv[4] = {v.x, v.y, v.z, v.w};
                float pp[4] = {pv.x, pv.y, pv.z, pv.w};
                float rr[4];
                #pragma unroll
                for (int m = 0; m < 4; ++m) {
                    float coord = (t & 1) ? fi : (float)(jg0 + 4 * q + m);
                    float sin_ = (t < 2) ? vv[m] : pp[m];
                    float ein_ = (t < 2) ? pp[m] : vv[m];
                    float ixy = (sigm(sin_) * 1.05f - 0.025f + coord) * (1.0f / 76.0f);
                    float wh2 = __expf(ein_) * anc;
                    rr[m] = (t < 2) ? (ixy - wh2) : (ixy + wh2);
                }
                r0 = rr[0]; r1 = rr[1]; r2 = rr[2]; r3 = rr[3];
            }
            float* lp = &lds[(4 * q) * NCH + c];
            lp[0]       = r0;
            lp[NCH]     = r1;
            lp[2 * NCH] = r2;
            lp[3 * NCH] = r3;
        }
    }
    __syncthreads();

    // ---- phase C: contiguous float4 dump ----
    float4* __restrict__ dv = (float4*)dst;
    const float4* lv = (const float4*)lds;
    #pragma unroll
    for (int k = 0; k < NIT; ++k) {
        int e = threadIdx.x + BLOCK * k;
        if (e < NU) dv[e] = lv[e];
    }
}

__global__ __launch_bounds__(BLOCK, 8) void det_kernel(const float* __restrict__ in,
                                                       float* __restrict__ out) {
    __shared__ float lds[NCH * 20];    // 20400 B -> 8 blocks/CU

    int hw = blockIdx.x;
    int L  = (hw & 7) * CHUNK + (hw >> 3);
    int jq = L & 3;
    int L2 = L >> 2;
    int i  = L2 % GW;
    int b  = L2 / GW;
    const int j0 = jq * 20;

    const float* __restrict__ src =
        in + (size_t)b * (NCH * HW) + (size_t)i * GW + j0;
    float* __restrict__ dst =
        out + ((size_t)b * 17328 + (size_t)i * 228) * NATTR + (size_t)j0 * NCH;
    const float fi = (float)i;

    if (jq != 3) {
        run_quarter<5>(src, dst, lds, j0, fi);
    } else {
        run_quarter<4>(src, dst, lds, j0, fi);
    }
}

extern "C" void kernel_launch(void* const* d_in, const int* in_sizes, int n_in,
                              void* d_out, int out_size, void* d_ws, size_t ws_size,
                              hipStream_t stream) {
    const float* x = (const float*)d_in[0];
    float* out = (float*)d_out;
    det_kernel<<<NWG, BLOCK, 0, stream>>>(x, out);
}

// Round 13
// 59.442 us; speedup vs baseline: 1.4260x; 1.4260x over previous
//
#include <hip/hip_runtime.h>
#include <math.h>

// DetectionLayer: x(32,255,76,76) f32 -> out(32,17328,85) f32
// R8 structure (measured best, 78.5us) + NON-TEMPORAL dump stores.
// Output is write-once/never-read: nt stores skip L2/L3 write-allocate,
// keeping the 188MB input resident in L3 across graph replays
// (R8 FETCH_SIZE=92MB showed it was only half-resident).
// NOTE: __builtin_nontemporal_store requires a native clang vector type,
// not HIP_vector_type -> use ext_vector_type(4) for the dump.
//
// Block (512 thr) = (b, row i, j-half). jh=0: cols [0,40), jh=1: cols [40,76).
// Phase A: batched float4 loads (NQ=10|9 vec4/channel, 16B-aligned).
// Phase B: transform in registers; corner channels (t<4, 12/255) load the
//          cache-warm partner channel (c+-2) and finalize inline; a = c/85
//          exact. LDS write in output layout lds[j*255+c].
// Phase C: one __syncthreads (loads already consumed -> cheap drain), then
//          contiguous float4 NT dump (10200|9180 floats, 16B-aligned).
// LDS 40800B -> 4 blocks/CU x 8 waves = 32 waves/CU, 1 barrier per block.
// XCD swizzle: logical (b,i,jh), jh fastest; 4864%8==0 -> bijective.

#define NCH    255
#define NATTR  85
#define HW     5776
#define GW     76
#define NBATCH 32
#define BLOCK  512
#define NWG    (NBATCH * GW * 2)   // 4864
#define CHUNK  (NWG / 8)           // 608

typedef float f32x4 __attribute__((ext_vector_type(4)));

__device__ __forceinline__ float sigm(float x) {
    return __builtin_amdgcn_rcpf(1.0f + __expf(-x));
}

template<int NQ>   // float4 units per channel: 10 (jh=0) or 9 (jh=1)
__device__ __forceinline__ void run_half(const float* __restrict__ src,
                                         float* __restrict__ dst,
                                         float* __restrict__ lds,
                                         int jg0, float fi) {
    constexpr int NU  = NCH * NQ;                  // 2550 / 2295 vec4 units
    constexpr int NIT = (NU + BLOCK - 1) / BLOCK;  // 5 / 5

    float4 xv[NIT];

    // ---- phase A: batched float4 loads ----
    #pragma unroll
    for (int k = 0; k < NIT; ++k) {
        int e = threadIdx.x + BLOCK * k;
        if (e < NU) {
            int c = e / NQ, q = e - c * NQ;
            xv[k] = *(const float4*)(src + (size_t)c * HW + 4 * q);
        }
    }

    // ---- phase B: transform + output-layout LDS write ----
    #pragma unroll
    for (int k = 0; k < NIT; ++k) {
        int e = threadIdx.x + BLOCK * k;
        if (e < NU) {
            int c = e / NQ, q = e - c * NQ;
            int a = c / 85;              // exact (compiler magic-mul)
            int t = c - 85 * a;
            float4 v = xv[k];
            float r0, r1, r2, r3;
            if (t >= 4) {
                r0 = sigm(v.x); r1 = sigm(v.y); r2 = sigm(v.z); r3 = sigm(v.w);
            } else {
                int cp = (t < 2) ? c + 2 : c - 2;      // partner (cache-warm)
                float4 pv = *(const float4*)(src + (size_t)cp * HW + 4 * q);
                float ancw = (a == 0) ? 10.f : (a == 1) ? 16.f : 33.f;
                float anch = (a == 0) ? 13.f : (a == 1) ? 30.f : 23.f;
                float anc  = ((t & 1) ? anch : ancw) * (0.5f / 608.f);
                float vv[4] = {v.x, v.y, v.z, v.w};
                float pp[4] = {pv.x, pv.y, pv.z, pv.w};
                float rr[4];
                #pragma unroll
                for (int m = 0; m < 4; ++m) {
                    float coord = (t & 1) ? fi : (float)(jg0 + 4 * q + m);
                    float sin_ = (t < 2) ? vv[m] : pp[m];   // sigmoid input
                    float ein_ = (t < 2) ? pp[m] : vv[m];   // exp input
                    float ixy = (sigm(sin_) * 1.05f - 0.025f + coord) * (1.0f / 76.0f);
                    float wh2 = __expf(ein_) * anc;
                    rr[m] = (t < 2) ? (ixy - wh2) : (ixy + wh2);
                }
                r0 = rr[0]; r1 = rr[1]; r2 = rr[2]; r3 = rr[3];
            }
            float* lp = &lds[(4 * q) * NCH + c];
            lp[0]       = r0;
            lp[NCH]     = r1;
            lp[2 * NCH] = r2;
            lp[3 * NCH] = r3;
        }
    }
    __syncthreads();

    // ---- phase C: contiguous float4 NON-TEMPORAL dump ----
    f32x4* __restrict__ dv = (f32x4*)dst;
    const f32x4* lv = (const f32x4*)lds;
    #pragma unroll
    for (int k = 0; k < NIT; ++k) {
        int e = threadIdx.x + BLOCK * k;
        if (e < NU) __builtin_nontemporal_store(lv[e], &dv[e]);
    }
}

__global__ __launch_bounds__(BLOCK, 8) void det_kernel(const float* __restrict__ in,
                                                       float* __restrict__ out) {
    __shared__ float lds[NCH * 40];    // 40800 B -> 4 blocks/CU

    int hw = blockIdx.x;
    int L  = (hw & 7) * CHUNK + (hw >> 3);
    int jh = L & 1;
    int L2 = L >> 1;
    int i  = L2 % GW;
    int b  = L2 / GW;

    const float* __restrict__ src = in + (size_t)b * (NCH * HW) + (size_t)i * GW;
    float* __restrict__ dst = out + ((size_t)b * 17328 + (size_t)i * 228) * NATTR;
    const float fi = (float)i;

    if (jh == 0) {
        run_half<10>(src, dst, lds, 0, fi);
    } else {
        run_half<9>(src + 40, dst + 40 * NCH, lds, 40, fi);
    }
}

extern "C" void kernel_launch(void* const* d_in, const int* in_sizes, int n_in,
                              void* d_out, int out_size, void* d_ws, size_t ws_size,
                              hipStream_t stream) {
    const float* x = (const float*)d_in[0];
    float* out = (float*)d_out;
    det_kernel<<<NWG, BLOCK, 0, stream>>>(x, out);
}

// Round 14
// 59.337 us; speedup vs baseline: 1.4286x; 1.0018x over previous
//
#include <hip/hip_runtime.h>
#include <math.h>

// DetectionLayer: x(32,255,76,76) f32 -> out(32,17328,85) f32
// R13 structure (NT-store, 59.4us wall) + LOAD-BATCHING FENCE.
// R13's VGPR_Count=28 proves the compiler sank the 5 batched float4 loads
// into the transform loop (load->use->load->use), exposing one HBM latency
// per iteration. An asm memory fence between the load loop and the xform
// loop pins all 5 global_load_dwordx4 before any use: one latency per tile.
//
// Block (512 thr) = (b, row i, j-half). jh=0: cols [0,40), jh=1: cols [40,76).
// Phase A: batched float4 loads (NQ=10|9 vec4/channel, 16B-aligned) + fence.
// Phase B: transform in registers; corner channels (t<4, 12/255) load the
//          cache-warm partner channel (c+-2) and finalize inline; a = c/85
//          exact. LDS write in output layout lds[j*255+c].
// Phase C: one __syncthreads, then contiguous float4 NT dump.
// LDS 40800B -> 4 blocks/CU x 8 waves = 32 waves/CU, 1 barrier per block.
// XCD swizzle: logical (b,i,jh), jh fastest; 4864%8==0 -> bijective.

#define NCH    255
#define NATTR  85
#define HW     5776
#define GW     76
#define NBATCH 32
#define BLOCK  512
#define NWG    (NBATCH * GW * 2)   // 4864
#define CHUNK  (NWG / 8)           // 608

typedef float f32x4 __attribute__((ext_vector_type(4)));

__device__ __forceinline__ float sigm(float x) {
    return __builtin_amdgcn_rcpf(1.0f + __expf(-x));
}

template<int NQ>   // float4 units per channel: 10 (jh=0) or 9 (jh=1)
__device__ __forceinline__ void run_half(const float* __restrict__ src,
                                         float* __restrict__ dst,
                                         float* __restrict__ lds,
                                         int jg0, float fi) {
    constexpr int NU  = NCH * NQ;                  // 2550 / 2295 vec4 units
    constexpr int NIT = (NU + BLOCK - 1) / BLOCK;  // 5 / 5

    float4 xv[NIT];

    // ---- phase A: batched float4 loads ----
    #pragma unroll
    for (int k = 0; k < NIT; ++k) {
        int e = threadIdx.x + BLOCK * k;
        if (e < NU) {
            int c = e / NQ, q = e - c * NQ;
            xv[k] = *(const float4*)(src + (size_t)c * HW + 4 * q);
        }
    }
    // fence: forbid sinking the loads into the transform loop
    asm volatile("" ::: "memory");

    // ---- phase B: transform + output-layout LDS write ----
    #pragma unroll
    for (int k = 0; k < NIT; ++k) {
        int e = threadIdx.x + BLOCK * k;
        if (e < NU) {
            int c = e / NQ, q = e - c * NQ;
            int a = c / 85;              // exact (compiler magic-mul)
            int t = c - 85 * a;
            float4 v = xv[k];
            float r0, r1, r2, r3;
            if (t >= 4) {
                r0 = sigm(v.x); r1 = sigm(v.y); r2 = sigm(v.z); r3 = sigm(v.w);
            } else {
                int cp = (t < 2) ? c + 2 : c - 2;      // partner (cache-warm)
                float4 pv = *(const float4*)(src + (size_t)cp * HW + 4 * q);
                float ancw = (a == 0) ? 10.f : (a == 1) ? 16.f : 33.f;
                float anch = (a == 0) ? 13.f : (a == 1) ? 30.f : 23.f;
                float anc  = ((t & 1) ? anch : ancw) * (0.5f / 608.f);
                float vv[4] = {v.x, v.y, v.z, v.w};
                float pp[4] = {pv.x, pv.y, pv.z, pv.w};
                float rr[4];
                #pragma unroll
                for (int m = 0; m < 4; ++m) {
                    float coord = (t & 1) ? fi : (float)(jg0 + 4 * q + m);
                    float sin_ = (t < 2) ? vv[m] : pp[m];   // sigmoid input
                    float ein_ = (t < 2) ? pp[m] : vv[m];   // exp input
                    float ixy = (sigm(sin_) * 1.05f - 0.025f + coord) * (1.0f / 76.0f);
                    float wh2 = __expf(ein_) * anc;
                    rr[m] = (t < 2) ? (ixy - wh2) : (ixy + wh2);
                }
                r0 = rr[0]; r1 = rr[1]; r2 = rr[2]; r3 = rr[3];
            }
            float* lp = &lds[(4 * q) * NCH + c];
            lp[0]       = r0;
            lp[NCH]     = r1;
            lp[2 * NCH] = r2;
            lp[3 * NCH] = r3;
        }
    }
    __syncthreads();

    // ---- phase C: contiguous float4 NON-TEMPORAL dump ----
    f32x4* __restrict__ dv = (f32x4*)dst;
    const f32x4* lv = (const f32x4*)lds;
    #pragma unroll
    for (int k = 0; k < NIT; ++k) {
        int e = threadIdx.x + BLOCK * k;
        if (e < NU) __builtin_nontemporal_store(lv[e], &dv[e]);
    }
}

__global__ __launch_bounds__(BLOCK, 8) void det_kernel(const float* __restrict__ in,
                                                       float* __restrict__ out) {
    __shared__ float lds[NCH * 40];    // 40800 B -> 4 blocks/CU

    int hw = blockIdx.x;
    int L  = (hw & 7) * CHUNK + (hw >> 3);
    int jh = L & 1;
    int L2 = L >> 1;
    int i  = L2 % GW;
    int b  = L2 / GW;

    const float* __restrict__ src = in + (size_t)b * (NCH * HW) + (size_t)i * GW;
    float* __restrict__ dst = out + ((size_t)b * 17328 + (size_t)i * 228) * NATTR;
    const float fi = (float)i;

    if (jh == 0) {
        run_half<10>(src, dst, lds, 0, fi);
    } else {
        run_half<9>(src + 40, dst + 40 * NCH, lds, 40, fi);
    }
}

extern "C" void kernel_launch(void* const* d_in, const int* in_sizes, int n_in,
                              void* d_out, int out_size, void* d_ws, size_t ws_size,
                              hipStream_t stream) {
    const float* x = (const float*)d_in[0];
    float* out = (float*)d_out;
    det_kernel<<<NWG, BLOCK, 0, stream>>>(x, out);
}